// Round 7
// baseline (335.401 us; speedup 1.0000x reference)
//
#include <hip/hip_runtime.h>
#include <math.h>

// Problem constants
constexpr int KDIM = 784;    // feature dim
constexpr int NA   = 30;     // number of angles
constexpr int RPW  = 16;     // rows per wave
constexpr int NRND = 12;     // full rounds: 12*64 = 768
// tail: cols 768..783 (16 cols)

__global__ __launch_bounds__(64)
void fused_rnn_circuit(const float* __restrict__ X,
                       const float* __restrict__ W,
                       const float* __restrict__ Bv,
                       float* __restrict__ out)
{
    const int l = threadIdx.x;           // lane
    const int r = l & 15;                // row within wave's 16-row strip
    const int g = l >> 4;                // col-group 0..3 (K-split across lanes)
    const long long row = (long long)blockIdx.x * RPW + r;

    // Lane (r,g) covers cols { j*64 + 16m + 4g + e : m=0..3, e=0..3 } each round,
    // plus tail cols 768 + 4g + e. Union over g = all 784 cols, disjoint.
    const float* xrow = X + row * (long long)KDIM + 4 * g;

    float acc[NA];
#pragma unroll
    for (int a = 0; a < NA; ++a) acc[a] = 0.f;

    // register double-buffer for X (prefetch one round ahead)
    float4 cur[4], nxt[4];
#pragma unroll
    for (int m = 0; m < 4; ++m)
        cur[m] = *reinterpret_cast<const float4*>(xrow + 16 * m);

    float4 xt = make_float4(0.f, 0.f, 0.f, 0.f);   // tail X quad

#pragma unroll 2
    for (int j = 0; j < NRND; ++j) {
        // ---- prefetch next round's X into registers (hides under 480 FMAs) ----
        if (j + 1 < NRND) {
#pragma unroll
            for (int m = 0; m < 4; ++m)
                nxt[m] = *reinterpret_cast<const float4*>(xrow + (j + 1) * 64 + 16 * m);
        } else {
            xt = *reinterpret_cast<const float4*>(xrow + NRND * 64);   // cols 768+4g..+3
        }

        // ---- 30 angles x 16 cols FMA; W quads are L1/L2-hot vector loads ----
        const float* wb = W + j * 64 + 4 * g;
#pragma unroll
        for (int a = 0; a < NA; ++a) {
            const float* wa = wb + (long long)a * KDIM;
            const float4 w0 = *reinterpret_cast<const float4*>(wa);
            const float4 w1 = *reinterpret_cast<const float4*>(wa + 16);
            const float4 w2 = *reinterpret_cast<const float4*>(wa + 32);
            const float4 w3 = *reinterpret_cast<const float4*>(wa + 48);
            float s = acc[a];
            s = fmaf(cur[0].x, w0.x, s); s = fmaf(cur[0].y, w0.y, s);
            s = fmaf(cur[0].z, w0.z, s); s = fmaf(cur[0].w, w0.w, s);
            s = fmaf(cur[1].x, w1.x, s); s = fmaf(cur[1].y, w1.y, s);
            s = fmaf(cur[1].z, w1.z, s); s = fmaf(cur[1].w, w1.w, s);
            s = fmaf(cur[2].x, w2.x, s); s = fmaf(cur[2].y, w2.y, s);
            s = fmaf(cur[2].z, w2.z, s); s = fmaf(cur[2].w, w2.w, s);
            s = fmaf(cur[3].x, w3.x, s); s = fmaf(cur[3].y, w3.y, s);
            s = fmaf(cur[3].z, w3.z, s); s = fmaf(cur[3].w, w3.w, s);
            acc[a] = s;
        }
#pragma unroll
        for (int m = 0; m < 4; ++m) cur[m] = nxt[m];
    }

    // ---- tail: cols 768..783 (4 per lane-group) ----
    {
        const float* wb = W + NRND * 64 + 4 * g;
#pragma unroll
        for (int a = 0; a < NA; ++a) {
            const float4 wt = *reinterpret_cast<const float4*>(wb + (long long)a * KDIM);
            float s = acc[a];
            s = fmaf(xt.x, wt.x, s); s = fmaf(xt.y, wt.y, s);
            s = fmaf(xt.z, wt.z, s); s = fmaf(xt.w, wt.w, s);
            acc[a] = s;
        }
    }

    // ---- butterfly reduction over the 4 col-groups (lanes r, r+16, r+32, r+48) ----
#pragma unroll
    for (int a = 0; a < NA; ++a) {
        acc[a] += __shfl_xor(acc[a], 16, 64);
        acc[a] += __shfl_xor(acc[a], 32, 64);
    }

    // ---- lanes 0..15: bias, 4-qubit circuit in registers, store ----
    if (l < 16) {
        float ap[NA];
#pragma unroll
        for (int a = 0; a < NA; ++a) ap[a] = acc[a] + Bv[a];   // Bv uniform -> s_load

        float sr[16], si[16];
#pragma unroll
        for (int q = 0; q < 16; ++q) { sr[q] = 0.f; si[q] = 0.f; }
        sr[0] = 1.f;

        auto u3 = [&](int wq, float th, float ph, float la) {
            float ch, sh;  __sincosf(0.5f * th, &sh, &ch);
            float elr, eli; __sincosf(la, &eli, &elr);
            float epr, epi; __sincosf(ph, &epi, &epr);
            float eer = epr * elr - epi * eli;   // ep*el
            float eei = epr * eli + epi * elr;
            const int m = 1 << (3 - wq);
#pragma unroll
            for (int idx = 0; idx < 16; ++idx) {
                if (idx & m) continue;
                int i1 = idx + m;
                float o0r = sr[idx], o0i = si[idx], o1r = sr[i1], o1i = si[i1];
                float e1r = elr * o1r - eli * o1i;
                float e1i = elr * o1i + eli * o1r;
                sr[idx] = ch * o0r - sh * e1r;
                si[idx] = ch * o0i - sh * e1i;
                float p0r = epr * o0r - epi * o0i;
                float p0i = epr * o0i + epi * o0r;
                float q1r = eer * o1r - eei * o1i;
                float q1i = eer * o1i + eei * o1r;
                sr[i1] = sh * p0r + ch * q1r;
                si[i1] = sh * p0i + ch * q1i;
            }
        };

#pragma unroll
        for (int lay = 0; lay < 2; ++lay) {
            const int base = lay * 15;
#pragma unroll
            for (int i = 0; i < 3; ++i) {
                {
                    float th = ap[base + i * 4];
                    float ch, sh; __sincosf(0.5f * th, &sh, &ch);
                    const int m1 = 1 << (3 - i);
                    const int m2 = 1 << (2 - i);
#pragma unroll
                    for (int b0 = 0; b0 < 16; ++b0) {
                        if (b0 & (m1 | m2)) continue;
                        int i00 = b0, i01 = b0 + m2, i10 = b0 + m1, i11 = b0 + m1 + m2;
                        float o00r = sr[i00], o00i = si[i00], o11r = sr[i11], o11i = si[i11];
                        sr[i00] = ch * o00r + sh * o11i;
                        si[i00] = ch * o00i - sh * o11r;
                        sr[i11] = ch * o11r + sh * o00i;
                        si[i11] = ch * o11i - sh * o00r;
                        float o01r = sr[i01], o01i = si[i01], o10r = sr[i10], o10i = si[i10];
                        sr[i01] = ch * o01r + sh * o10i;
                        si[i01] = ch * o01i - sh * o10r;
                        sr[i10] = ch * o10r + sh * o01i;
                        si[i10] = ch * o10i - sh * o01r;
                    }
                }
                u3(i, ap[base + i * 4 + 1], ap[base + i * 4 + 2], ap[base + i * 4 + 3]);
            }
            u3(3, ap[base + 12], ap[base + 13], ap[base + 14]);
        }

        float* orow = out + row * 32;
#pragma unroll
        for (int q = 0; q < 8; ++q) {
            float4 v = make_float4(sr[2 * q], si[2 * q], sr[2 * q + 1], si[2 * q + 1]);
            *reinterpret_cast<float4*>(orow + q * 4) = v;
        }
    }
}

extern "C" void kernel_launch(void* const* d_in, const int* in_sizes, int n_in,
                              void* d_out, int out_size, void* d_ws, size_t ws_size,
                              hipStream_t stream) {
    const float* X  = (const float*)d_in[0];
    const float* W  = (const float*)d_in[1];
    const float* Bv = (const float*)d_in[2];
    float* out = (float*)d_out;

    const int Bn = in_sizes[0] / KDIM;   // 65536
    dim3 grid(Bn / RPW);                 // 4096 single-wave blocks
    fused_rnn_circuit<<<grid, 64, 0, stream>>>(X, W, Bv, out);
}

// Round 8
// 230.190 us; speedup vs baseline: 1.4571x; 1.4571x over previous
//
#include <hip/hip_runtime.h>
#include <math.h>

// Problem constants
constexpr int KDIM  = 784;   // feature dim
constexpr int NA    = 30;    // number of angles
constexpr int KC    = 32;    // k-chunk columns
constexpr int ROWS  = 64;    // rows per block (= lane)
constexpr int NW    = 4;     // waves per block
constexpr int NT    = 256;   // threads
constexpr int APT   = 8;     // angles per wave
constexpr int NCH   = 24;    // full chunks: 24*32 = 768
constexpr int KTAIL = 16;    // 784 - 768

#define WAIT_VM(N) asm volatile("s_waitcnt vmcnt(" #N ")" ::: "memory")
#define BARRIER()  do { __builtin_amdgcn_s_barrier(); asm volatile("" ::: "memory"); } while (0)

__global__ __launch_bounds__(NT)   // no min-occ arg: avoid forced VGPR cap / spill
void fused_rnn_circuit(const float* __restrict__ X,
                       const float* __restrict__ W,
                       const float* __restrict__ Bv,
                       float* __restrict__ out)
{
    const int t    = threadIdx.x;
    const int lane = t & 63;
    const int w    = t >> 6;                 // wave id 0..3
    const long long row0 = (long long)blockIdx.x * ROWS;

    // 3 staging buffers (8 KB each) + tail tile (4 KB) = 28 KB.
    // Slot t of a buffer holds (row = t>>3 [+32 for 2nd call], pos p = t&7);
    // position p stores global colblock g = p ^ (row&7)  [XOR involution].
    __shared__ float xs[3][ROWS * KC];
    __shared__ float xst[ROWS * 16];

    const int srow = t >> 3;                 // 0..31
    const int sq   = (t & 7) ^ (srow & 7);
    const float* gsrc0 = X + (row0 + srow)      * (long long)KDIM + sq * 4;
    const float* gsrc1 = X + (row0 + 32 + srow) * (long long)KDIM + sq * 4;

    auto stage = [&](int c, int buf) {
        __builtin_amdgcn_global_load_lds(
            (const __attribute__((address_space(1))) void*)(gsrc0 + c * KC),
            (__attribute__((address_space(3))) void*)&xs[buf][w * 256], 16, 0, 0);
        __builtin_amdgcn_global_load_lds(
            (const __attribute__((address_space(1))) void*)(gsrc1 + c * KC),
            (__attribute__((address_space(3))) void*)&xs[buf][1024 + w * 256], 16, 0, 0);
    };

    // ---- compute roles: row r = lane; angles w*8..w*8+7 (clamped dupes in wave 3) ----
    const int r  = lane;
    const int rx = r & 7;
    int arj[APT];
#pragma unroll
    for (int j = 0; j < APT; ++j) {
        int a = w * APT + j;
        arj[j] = __builtin_amdgcn_readfirstlane(a < NA ? a : NA - 1);
    }

    float acc[APT];
#pragma unroll
    for (int j = 0; j < APT; ++j) acc[j] = 0.f;

    auto compute = [&](int j, int buf) {
        float xv[KC];
#pragma unroll
        for (int q = 0; q < 8; ++q) {
            float4 v = *reinterpret_cast<const float4*>(&xs[buf][r * KC + ((q ^ rx) << 2)]);
            xv[4 * q + 0] = v.x; xv[4 * q + 1] = v.y;
            xv[4 * q + 2] = v.z; xv[4 * q + 3] = v.w;
        }
#pragma unroll
        for (int a = 0; a < APT; ++a) {
            const float* wr = W + (long long)arj[a] * KDIM + j * KC;   // SGPR base -> s_load
            float s = acc[a];
#pragma unroll
            for (int k = 0; k < KC; ++k) s = fmaf(xv[k], wr[k], s);
            acc[a] = s;
        }
    };

    // ---- prologue: stage chunks 0,1 + tail; wait only for chunk 0 ----
    stage(0, 0);
    stage(1, 1);
    {   // tail: slot t -> row t>>2, quad t&3 (linear [64][16] layout)
        const float* gp = X + (row0 + (t >> 2)) * (long long)KDIM + NCH * KC + (t & 3) * 4;
        __builtin_amdgcn_global_load_lds(
            (const __attribute__((address_space(1))) void*)gp,
            (__attribute__((address_space(3))) void*)&xst[w * 256], 16, 0, 0);
    }
    WAIT_VM(3);          // 5 outstanding; oldest 2 (= chunk 0) must land
    BARRIER();

    // ---- main loop: 2-ahead staging, counted vmcnt (never 0) ----
    // invariant at iter j: tile j ready in buf j%3; stage(j+2) -> buf (j+2)%3 (freed at j-1)
    for (int jj = 0; jj < 21; jj += 3) {
        stage(jj + 2, 2); compute(jj + 0, 0); WAIT_VM(2); BARRIER();
        stage(jj + 3, 0); compute(jj + 1, 1); WAIT_VM(2); BARRIER();
        stage(jj + 4, 1); compute(jj + 2, 2); WAIT_VM(2); BARRIER();
    }
    // epilogue peel: j = 21, 22, 23
    stage(23, 2); compute(21, 0); WAIT_VM(2); BARRIER();
    compute(22, 1);               WAIT_VM(0); BARRIER();
    compute(23, 2);

    // ---- tail: cols 768..783 from xst (staged at prologue, long since published) ----
    {
        float xv[KTAIL];
#pragma unroll
        for (int q = 0; q < 4; ++q) {
            float4 v = *reinterpret_cast<const float4*>(&xst[r * 16 + 4 * q]);
            xv[4 * q + 0] = v.x; xv[4 * q + 1] = v.y;
            xv[4 * q + 2] = v.z; xv[4 * q + 3] = v.w;
        }
#pragma unroll
        for (int a = 0; a < APT; ++a) {
            const float* wr = W + (long long)arj[a] * KDIM + NCH * KC;
            float s = acc[a];
#pragma unroll
            for (int k = 0; k < KTAIL; ++k) s = fmaf(xv[k], wr[k], s);
            acc[a] = s;
        }
    }

    // ---- gather angles (+bias) into LDS (aliased over xs[0..1]; those tiles are dead:
    //      xs[0] last read at j=21 (barrier after), xs[1] at j=22 (barrier after);
    //      only xs[2] may still be in use by other waves, and we don't touch it) ----
    float (*ang)[33] = reinterpret_cast<float (*)[33]>(&xs[0][0]);   // 2112 floats
#pragma unroll
    for (int j = 0; j < APT; ++j) {
        int a = w * APT + j;
        if (a < NA) ang[r][a] = acc[j] + Bv[a];
    }
    __syncthreads();

    // ---- circuit: wave 0 only, one thread per row ----
    if (t < 64) {
        const float* ap = ang[t];

        float sr[16], si[16];
#pragma unroll
        for (int q = 0; q < 16; ++q) { sr[q] = 0.f; si[q] = 0.f; }
        sr[0] = 1.f;

        auto u3 = [&](int wq, float th, float ph, float la) {
            float ch, sh;  __sincosf(0.5f * th, &sh, &ch);
            float elr, eli; __sincosf(la, &eli, &elr);
            float epr, epi; __sincosf(ph, &epi, &epr);
            float eer = epr * elr - epi * eli;   // ep*el
            float eei = epr * eli + epi * elr;
            const int m = 1 << (3 - wq);
#pragma unroll
            for (int idx = 0; idx < 16; ++idx) {
                if (idx & m) continue;
                int i1 = idx + m;
                float o0r = sr[idx], o0i = si[idx], o1r = sr[i1], o1i = si[i1];
                float e1r = elr * o1r - eli * o1i;
                float e1i = elr * o1i + eli * o1r;
                sr[idx] = ch * o0r - sh * e1r;
                si[idx] = ch * o0i - sh * e1i;
                float p0r = epr * o0r - epi * o0i;
                float p0i = epr * o0i + epi * o0r;
                float q1r = eer * o1r - eei * o1i;
                float q1i = eer * o1i + eei * o1r;
                sr[i1] = sh * p0r + ch * q1r;
                si[i1] = sh * p0i + ch * q1i;
            }
        };

#pragma unroll
        for (int lay = 0; lay < 2; ++lay) {
            const int base = lay * 15;
#pragma unroll
            for (int i = 0; i < 3; ++i) {
                {
                    float th = ap[base + i * 4];
                    float ch, sh; __sincosf(0.5f * th, &sh, &ch);
                    const int m1 = 1 << (3 - i);
                    const int m2 = 1 << (2 - i);
#pragma unroll
                    for (int b0 = 0; b0 < 16; ++b0) {
                        if (b0 & (m1 | m2)) continue;
                        int i00 = b0, i01 = b0 + m2, i10 = b0 + m1, i11 = b0 + m1 + m2;
                        float o00r = sr[i00], o00i = si[i00], o11r = sr[i11], o11i = si[i11];
                        sr[i00] = ch * o00r + sh * o11i;
                        si[i00] = ch * o00i - sh * o11r;
                        sr[i11] = ch * o11r + sh * o00i;
                        si[i11] = ch * o11i - sh * o00r;
                        float o01r = sr[i01], o01i = si[i01], o10r = sr[i10], o10i = si[i10];
                        sr[i01] = ch * o01r + sh * o10i;
                        si[i01] = ch * o01i - sh * o10r;
                        sr[i10] = ch * o10r + sh * o01i;
                        si[i10] = ch * o10i - sh * o01r;
                    }
                }
                u3(i, ap[base + i * 4 + 1], ap[base + i * 4 + 2], ap[base + i * 4 + 3]);
            }
            u3(3, ap[base + 12], ap[base + 13], ap[base + 14]);
        }

        float* orow = out + (row0 + t) * 32;
#pragma unroll
        for (int q = 0; q < 8; ++q) {
            float4 v = make_float4(sr[2 * q], si[2 * q], sr[2 * q + 1], si[2 * q + 1]);
            *reinterpret_cast<float4*>(orow + q * 4) = v;
        }
    }
}

extern "C" void kernel_launch(void* const* d_in, const int* in_sizes, int n_in,
                              void* d_out, int out_size, void* d_ws, size_t ws_size,
                              hipStream_t stream) {
    const float* X  = (const float*)d_in[0];
    const float* W  = (const float*)d_in[1];
    const float* Bv = (const float*)d_in[2];
    float* out = (float*)d_out;

    const int Bn = in_sizes[0] / KDIM;   // 65536
    dim3 grid(Bn / ROWS);                // 1024 blocks x 256 threads
    fused_rnn_circuit<<<grid, NT, 0, stream>>>(X, W, Bv, out);
}

// Round 9
// 154.837 us; speedup vs baseline: 2.1662x; 1.4867x over previous
//
#include <hip/hip_runtime.h>
#include <math.h>

// Problem constants
constexpr int KDIM  = 784;   // feature dim
constexpr int NA    = 30;    // number of angles
constexpr int ROWS  = 64;    // rows per block (= lane <-> row)
constexpr int NW    = 8;     // waves per block (K-split, 16 cols each per phase)
constexpr int NT    = 512;   // threads
constexpr int PC    = 128;   // columns per phase
constexpr int NPH   = 6;     // full phases: 6*128 = 768
constexpr int KTAIL = 16;    // 784 - 768

__global__ __launch_bounds__(NT)   // no min-occ arg (forced VGPR caps caused R2/R5 spills)
void fused_rnn_circuit(const float* __restrict__ X,
                       const float* __restrict__ W,
                       const float* __restrict__ Bv,
                       float* __restrict__ out)
{
    const int t    = threadIdx.x;
    const int lane = t & 63;
    const int w    = __builtin_amdgcn_readfirstlane(t >> 6);   // wave id 0..7 (SGPR)
    const long long row0 = (long long)blockIdx.x * ROWS;

    // Double-buffered phase tile: 64 rows x 128 cols x 4B x 2 = 64 KB (+4 KB tail).
    // Slot (16B) s = row*32 + p; position p stores global colquad
    // g = (p&24) | ((p&7) ^ (row&7))   [XOR swizzle, involution]
    // After the K-loop the 64 KB is re-used as part[8][64][32] for reduction.
    __shared__ float xs[2][ROWS * PC];
    __shared__ float xtail[ROWS * KTAIL];

    // ---- staging geometry: 2048 slots/phase, 512 threads -> 4 global_load_lds ----
    // call i: slot = i*512 + t -> row = i*16 + (t>>5), p = t&31
    const int trow = t >> 5;                 // 0..15
    const int p    = t & 31;
    const int g    = (p & 24) | ((p & 7) ^ (trow & 7));   // row&7 == trow&7 for all calls
    const float* gb = X + (row0 + trow) * (long long)KDIM + g * 4;

    auto stage = [&](int ph, int buf) {
        const float* s = gb + ph * PC;
#pragma unroll
        for (int i = 0; i < 4; ++i) {
            __builtin_amdgcn_global_load_lds(
                (const __attribute__((address_space(1))) void*)(s + (long long)(i * 16) * KDIM),
                (__attribute__((address_space(3))) void*)&xs[buf][i * 2048 + w * 256], 16, 0, 0);
        }
    };

    float acc[NA];
#pragma unroll
    for (int a = 0; a < NA; ++a) acc[a] = 0.f;

    // ---- prologue: stage phase 0 + tail tile ----
    stage(0, 0);
    if (t < 256) {   // waves 0..3 (wave-uniform branch): 64 rows x 16 cols -> 4 KB
        const float* gp = X + (row0 + (t >> 2)) * (long long)KDIM + NPH * PC + (t & 3) * 4;
        __builtin_amdgcn_global_load_lds(
            (const __attribute__((address_space(1))) void*)gp,
            (__attribute__((address_space(3))) void*)&xtail[w * 256], 16, 0, 0);
    }
    __syncthreads();

    // ---- K loop: 6 phases; wave w consumes cols ph*128 + w*16 .. +16 (all 30 angles) ----
    const int rx = lane & 7;
    for (int ph = 0; ph < NPH; ++ph) {
        const int buf = ph & 1;
        if (ph + 1 < NPH) stage(ph + 1, buf ^ 1);

        float xv[16];
#pragma unroll
        for (int qq = 0; qq < 4; ++qq) {
            const int q  = 4 * w + qq;                    // colquad 0..31
            const int pp = (q & 24) | ((q & 7) ^ rx);     // stored position
            float4 v = *reinterpret_cast<const float4*>(&xs[buf][lane * PC + pp * 4]);
            xv[4 * qq + 0] = v.x; xv[4 * qq + 1] = v.y;
            xv[4 * qq + 2] = v.z; xv[4 * qq + 3] = v.w;
        }

        const float* wb = W + ph * PC + w * 16;           // wave-uniform -> s_load
#pragma unroll
        for (int a = 0; a < NA; ++a) {
            const float* wr = wb + (long long)a * KDIM;
            float s = acc[a];
#pragma unroll
            for (int k = 0; k < 16; ++k) s = fmaf(xv[k], wr[k], s);
            acc[a] = s;
        }
        __syncthreads();   // phase tile consumed by all; next-phase loads drained
    }

    // ---- tail: cols 768..783, 2 per wave (staged at prologue) ----
    {
        const float x0 = xtail[lane * KTAIL + w * 2 + 0];
        const float x1 = xtail[lane * KTAIL + w * 2 + 1];
        const float* wbt = W + NPH * PC + w * 2;          // wave-uniform
#pragma unroll
        for (int a = 0; a < NA; ++a) {
            const float* wr = wbt + (long long)a * KDIM;
            acc[a] = fmaf(x1, wr[1], fmaf(x0, wr[0], acc[a]));
        }
    }

    // ---- write partials: part[w][lane][ab] at xs-flat[w*2048 + lane*32 + (ab^rx)*4] ----
    float* const xsf = &xs[0][0];   // 16384 floats, exactly part[8][64][32]
#pragma unroll
    for (int ab = 0; ab < 8; ++ab) {
        float4 v;
        v.x = (4 * ab + 0 < NA) ? acc[4 * ab + 0] : 0.f;
        v.y = (4 * ab + 1 < NA) ? acc[4 * ab + 1] : 0.f;
        v.z = (4 * ab + 2 < NA) ? acc[4 * ab + 2] : 0.f;
        v.w = (4 * ab + 3 < NA) ? acc[4 * ab + 3] : 0.f;
        *reinterpret_cast<float4*>(&xsf[w * 2048 + lane * 32 + ((ab ^ rx) << 2)]) = v;
    }
    __syncthreads();

    // ---- wave 0: reduce 8 partials, add bias, simulate circuit, store ----
    if (t < 64) {
        float red[32];
#pragma unroll
        for (int i = 0; i < 32; ++i) red[i] = 0.f;
#pragma unroll
        for (int ww = 0; ww < NW; ++ww) {
#pragma unroll
            for (int ab = 0; ab < 8; ++ab) {
                float4 v = *reinterpret_cast<const float4*>(
                    &xsf[ww * 2048 + lane * 32 + ((ab ^ rx) << 2)]);
                red[4 * ab + 0] += v.x; red[4 * ab + 1] += v.y;
                red[4 * ab + 2] += v.z; red[4 * ab + 3] += v.w;
            }
        }
        float ap[NA];
#pragma unroll
        for (int a = 0; a < NA; ++a) ap[a] = red[a] + Bv[a];   // uniform -> s_load

        float sr[16], si[16];
#pragma unroll
        for (int q = 0; q < 16; ++q) { sr[q] = 0.f; si[q] = 0.f; }
        sr[0] = 1.f;

        auto u3 = [&](int wq, float th, float ph_, float la) {
            float ch, sh;  __sincosf(0.5f * th, &sh, &ch);
            float elr, eli; __sincosf(la, &eli, &elr);
            float epr, epi; __sincosf(ph_, &epi, &epr);
            float eer = epr * elr - epi * eli;   // ep*el
            float eei = epr * eli + epi * elr;
            const int m = 1 << (3 - wq);
#pragma unroll
            for (int idx = 0; idx < 16; ++idx) {
                if (idx & m) continue;
                int i1 = idx + m;
                float o0r = sr[idx], o0i = si[idx], o1r = sr[i1], o1i = si[i1];
                float e1r = elr * o1r - eli * o1i;
                float e1i = elr * o1i + eli * o1r;
                sr[idx] = ch * o0r - sh * e1r;
                si[idx] = ch * o0i - sh * e1i;
                float p0r = epr * o0r - epi * o0i;
                float p0i = epr * o0i + epi * o0r;
                float q1r = eer * o1r - eei * o1i;
                float q1i = eer * o1i + eei * o1r;
                sr[i1] = sh * p0r + ch * q1r;
                si[i1] = sh * p0i + ch * q1i;
            }
        };

#pragma unroll
        for (int lay = 0; lay < 2; ++lay) {
            const int base = lay * 15;
#pragma unroll
            for (int i = 0; i < 3; ++i) {
                {
                    float th = ap[base + i * 4];
                    float ch, sh; __sincosf(0.5f * th, &sh, &ch);
                    const int m1 = 1 << (3 - i);
                    const int m2 = 1 << (2 - i);
#pragma unroll
                    for (int b0 = 0; b0 < 16; ++b0) {
                        if (b0 & (m1 | m2)) continue;
                        int i00 = b0, i01 = b0 + m2, i10 = b0 + m1, i11 = b0 + m1 + m2;
                        float o00r = sr[i00], o00i = si[i00], o11r = sr[i11], o11i = si[i11];
                        sr[i00] = ch * o00r + sh * o11i;
                        si[i00] = ch * o00i - sh * o11r;
                        sr[i11] = ch * o11r + sh * o00i;
                        si[i11] = ch * o11i - sh * o00r;
                        float o01r = sr[i01], o01i = si[i01], o10r = sr[i10], o10i = si[i10];
                        sr[i01] = ch * o01r + sh * o10i;
                        si[i01] = ch * o01i - sh * o10r;
                        sr[i10] = ch * o10r + sh * o01i;
                        si[i10] = ch * o10i - sh * o01r;
                    }
                }
                u3(i, ap[base + i * 4 + 1], ap[base + i * 4 + 2], ap[base + i * 4 + 3]);
            }
            u3(3, ap[base + 12], ap[base + 13], ap[base + 14]);
        }

        float* orow = out + (row0 + lane) * 32;
#pragma unroll
        for (int q = 0; q < 8; ++q) {
            float4 v = make_float4(sr[2 * q], si[2 * q], sr[2 * q + 1], si[2 * q + 1]);
            *reinterpret_cast<float4*>(orow + q * 4) = v;
        }
    }
}

extern "C" void kernel_launch(void* const* d_in, const int* in_sizes, int n_in,
                              void* d_out, int out_size, void* d_ws, size_t ws_size,
                              hipStream_t stream) {
    const float* X  = (const float*)d_in[0];
    const float* W  = (const float*)d_in[1];
    const float* Bv = (const float*)d_in[2];
    float* out = (float*)d_out;

    const int Bn = in_sizes[0] / KDIM;   // 65536
    dim3 grid(Bn / ROWS);                // 1024 blocks x 512 threads, 2 blocks/CU
    fused_rnn_circuit<<<grid, NT, 0, stream>>>(X, W, Bv, out);
}

// Round 10
// 138.281 us; speedup vs baseline: 2.4255x; 1.1197x over previous
//
#include <hip/hip_runtime.h>
#include <math.h>

// Problem constants
constexpr int KDIM = 784;    // feature dim
constexpr int NA   = 30;     // number of angles
constexpr int NW   = 4;      // waves per block (K-split)
constexpr int NT   = 256;    // threads per block
constexpr int GC   = 16;     // cols per group
// 49 groups of 16 cols: waves 0-2 take 12 groups (192 cols), wave 3 takes 13 (208).

#define WAIT_VM0() asm volatile("s_waitcnt vmcnt(0)" ::: "memory")

__global__ __launch_bounds__(NT)   // no min-occ arg (forced VGPR caps caused R2/R5 spills)
void fused_rnn_circuit(const float* __restrict__ X,
                       const float* __restrict__ W,
                       const float* __restrict__ Bv,
                       float* __restrict__ out)
{
    const int t    = threadIdx.x;
    const int lane = t & 63;
    const int wu   = __builtin_amdgcn_readfirstlane(t >> 6);   // wave id 0..3 (SGPR)
    const long long row0 = (long long)blockIdx.x * 64;

    // Wave-PRIVATE staging: xs[w] = 2048 floats (2 x 4KB buffers). 32 KB total.
    // Buffer layout: slot (16B) s = row*4 + p; position p holds col quad p ^ (row&3).
    // After the K-loop, wave w's own 8 KB region is reused as part[w][64][32].
    __shared__ float xs[NW][2048];

    // ---- staging geometry: 256 slots/group, 64 lanes -> 4 global_load_lds ----
    // call i: slot = i*64 + lane -> row = i*16 + (lane>>2), p = lane&3
    const int srl = lane >> 2;                  // 0..15
    const int sq  = (lane & 3) ^ (srl & 3);     // swizzled source quad (involution)
    const float* gs = X + (row0 + srl) * (long long)KDIM + sq * 4;

    const int k0 = wu * 192;                    // wave's column offset
    const int ng = (wu == 3) ? 13 : 12;         // groups for this wave

    float acc[NA];
#pragma unroll
    for (int a = 0; a < NA; ++a) acc[a] = 0.f;

    // ---- prologue: stage group 0 into buffer 0 ----
    {
        const float* s = gs + k0;
#pragma unroll
        for (int i = 0; i < 4; ++i)
            __builtin_amdgcn_global_load_lds(
                (const __attribute__((address_space(1))) void*)(s + (long long)(i * 16) * KDIM),
                (__attribute__((address_space(3))) void*)&xs[wu][i * 256], 16, 0, 0);
    }

    const int lx = lane & 3;
    // ---- K loop: NO barriers. wait own loads -> ds_read -> issue next stage -> FMAs ----
    for (int cc = 0; cc < ng; ++cc) {
        WAIT_VM0();                             // this wave's stage(cc) has landed

        float xv[16];
#pragma unroll
        for (int q = 0; q < 4; ++q) {
            float4 v = *reinterpret_cast<const float4*>(
                &xs[wu][(cc & 1) * 1024 + lane * 16 + ((q ^ lx) << 2)]);
            xv[4 * q + 0] = v.x; xv[4 * q + 1] = v.y;
            xv[4 * q + 2] = v.z; xv[4 * q + 3] = v.w;
        }

        if (cc + 1 < ng) {                      // issue next tile; latency hides under FMAs
            const float* s = gs + k0 + (cc + 1) * GC;
#pragma unroll
            for (int i = 0; i < 4; ++i)
                __builtin_amdgcn_global_load_lds(
                    (const __attribute__((address_space(1))) void*)(s + (long long)(i * 16) * KDIM),
                    (__attribute__((address_space(3))) void*)&xs[wu][((cc + 1) & 1) * 1024 + i * 256],
                    16, 0, 0);
        }

        const float* wb = W + k0 + cc * GC;     // wave-uniform -> s_load
#pragma unroll
        for (int a = 0; a < NA; ++a) {
            const float* wr = wb + (long long)a * KDIM;
            float s = acc[a];
#pragma unroll
            for (int k = 0; k < GC; ++k) s = fmaf(xv[k], wr[k], s);
            acc[a] = s;
        }
    }

    // ---- partials into this wave's OWN 8 KB region: part[w][lane][ab quads, rx-swizzled] ----
    const int rx = lane & 7;
#pragma unroll
    for (int ab = 0; ab < 8; ++ab) {
        float4 v;
        v.x = (4 * ab + 0 < NA) ? acc[4 * ab + 0] : 0.f;
        v.y = (4 * ab + 1 < NA) ? acc[4 * ab + 1] : 0.f;
        v.z = (4 * ab + 2 < NA) ? acc[4 * ab + 2] : 0.f;
        v.w = (4 * ab + 3 < NA) ? acc[4 * ab + 3] : 0.f;
        *reinterpret_cast<float4*>(&xs[wu][lane * 32 + ((ab ^ rx) << 2)]) = v;
    }
    __syncthreads();   // the ONLY block-wide barrier

    // ---- wave 0: reduce 4 partials, add bias, simulate circuit, store ----
    if (t < 64) {
        float red[32];
#pragma unroll
        for (int i = 0; i < 32; ++i) red[i] = 0.f;
#pragma unroll
        for (int ww = 0; ww < NW; ++ww) {
#pragma unroll
            for (int ab = 0; ab < 8; ++ab) {
                float4 v = *reinterpret_cast<const float4*>(
                    &xs[ww][lane * 32 + ((ab ^ rx) << 2)]);
                red[4 * ab + 0] += v.x; red[4 * ab + 1] += v.y;
                red[4 * ab + 2] += v.z; red[4 * ab + 3] += v.w;
            }
        }
        float ap[NA];
#pragma unroll
        for (int a = 0; a < NA; ++a) ap[a] = red[a] + Bv[a];   // uniform -> s_load

        float sr[16], si[16];
#pragma unroll
        for (int q = 0; q < 16; ++q) { sr[q] = 0.f; si[q] = 0.f; }
        sr[0] = 1.f;

        auto u3 = [&](int wq, float th, float ph_, float la) {
            float ch, sh;  __sincosf(0.5f * th, &sh, &ch);
            float elr, eli; __sincosf(la, &eli, &elr);
            float epr, epi; __sincosf(ph_, &epi, &epr);
            float eer = epr * elr - epi * eli;   // ep*el
            float eei = epr * eli + epi * elr;
            const int m = 1 << (3 - wq);
#pragma unroll
            for (int idx = 0; idx < 16; ++idx) {
                if (idx & m) continue;
                int i1 = idx + m;
                float o0r = sr[idx], o0i = si[idx], o1r = sr[i1], o1i = si[i1];
                float e1r = elr * o1r - eli * o1i;
                float e1i = elr * o1i + eli * o1r;
                sr[idx] = ch * o0r - sh * e1r;
                si[idx] = ch * o0i - sh * e1i;
                float p0r = epr * o0r - epi * o0i;
                float p0i = epr * o0i + epi * o0r;
                float q1r = eer * o1r - eei * o1i;
                float q1i = eer * o1i + eei * o1r;
                sr[i1] = sh * p0r + ch * q1r;
                si[i1] = sh * p0i + ch * q1i;
            }
        };

#pragma unroll
        for (int lay = 0; lay < 2; ++lay) {
            const int base = lay * 15;
#pragma unroll
            for (int i = 0; i < 3; ++i) {
                {
                    float th = ap[base + i * 4];
                    float ch, sh; __sincosf(0.5f * th, &sh, &ch);
                    const int m1 = 1 << (3 - i);
                    const int m2 = 1 << (2 - i);
#pragma unroll
                    for (int b0 = 0; b0 < 16; ++b0) {
                        if (b0 & (m1 | m2)) continue;
                        int i00 = b0, i01 = b0 + m2, i10 = b0 + m1, i11 = b0 + m1 + m2;
                        float o00r = sr[i00], o00i = si[i00], o11r = sr[i11], o11i = si[i11];
                        sr[i00] = ch * o00r + sh * o11i;
                        si[i00] = ch * o00i - sh * o11r;
                        sr[i11] = ch * o11r + sh * o00i;
                        si[i11] = ch * o11i - sh * o00r;
                        float o01r = sr[i01], o01i = si[i01], o10r = sr[i10], o10i = si[i10];
                        sr[i01] = ch * o01r + sh * o10i;
                        si[i01] = ch * o01i - sh * o10r;
                        sr[i10] = ch * o10r + sh * o01i;
                        si[i10] = ch * o10i - sh * o01r;
                    }
                }
                u3(i, ap[base + i * 4 + 1], ap[base + i * 4 + 2], ap[base + i * 4 + 3]);
            }
            u3(3, ap[base + 12], ap[base + 13], ap[base + 14]);
        }

        float* orow = out + (row0 + lane) * 32;
#pragma unroll
        for (int q = 0; q < 8; ++q) {
            float4 v = make_float4(sr[2 * q], si[2 * q], sr[2 * q + 1], si[2 * q + 1]);
            *reinterpret_cast<float4*>(orow + q * 4) = v;
        }
    }
}

extern "C" void kernel_launch(void* const* d_in, const int* in_sizes, int n_in,
                              void* d_out, int out_size, void* d_ws, size_t ws_size,
                              hipStream_t stream) {
    const float* X  = (const float*)d_in[0];
    const float* W  = (const float*)d_in[1];
    const float* Bv = (const float*)d_in[2];
    float* out = (float*)d_out;

    const int Bn = in_sizes[0] / KDIM;   // 65536
    dim3 grid(Bn / 64);                  // 1024 blocks x 256 threads, 5 blocks/CU
    fused_rnn_circuit<<<grid, NT, 0, stream>>>(X, W, Bv, out);
}